// Round 12
// baseline (277.391 us; speedup 1.0000x reference)
//
#include <hip/hip_runtime.h>
#include <hip/hip_bf16.h>

// Problem constants
#define BB   4096
#define INW  1024
#define HH   1024
#define KIN  2048      // IN + H
#define NG   5120      // 3H + 2H
#define KH   32        // inner hidden
#define FPG  10        // 16-col fragments per 160-col gate-group
#define NTG  32        // number of gate-groups (= H/32)

typedef __bf16 bf16;
typedef __bf16 bf16x4 __attribute__((ext_vector_type(4)));
typedef __bf16 bf16x8 __attribute__((ext_vector_type(8)));
typedef float  floatx4 __attribute__((ext_vector_type(4)));

#define GLD16(gp, lp)                                                          \
  __builtin_amdgcn_global_load_lds(                                            \
      (__attribute__((address_space(1))) const void*)(gp),                     \
      (__attribute__((address_space(3))) void*)(lp), 16, 0, 0)

// ---------------------------------------------------------------------------
// 1. prep (unchanged — sequential-row B shuffle, coalesced comb).
//    Wb chunk layout [F][kk][lane] with F = nt*10+f: chunk = (F*64 + kk)*64 +
//    (kq*16 + s) holds B[hcol = nt*32 + (f/5)*16 + s, gate f%5]
//    [k = kk*32 + kq*8 .. +7].
// ---------------------------------------------------------------------------
#define NCB  4096      // comb blocks: BB*KIN/8 threads / 256
#define NWB  1280      // Wb blocks: 32 nt x 10 f x 4 row-quarters

__global__ __launch_bounds__(256) void prep(
    const float* __restrict__ x, const float* __restrict__ h,
    const float* __restrict__ Wg, const float* __restrict__ Wc,
    bf16* __restrict__ comb, bf16* __restrict__ Wb) {
  int tid = threadIdx.x;
  if (blockIdx.x < NCB) {              // ---- comb: concat + cast ----
    int e = (blockIdx.x * 256 + tid) * 8;
    int b = e >> 11;          // / KIN
    int c = e & (KIN - 1);
    const float* src = (c < INW) ? (x + (size_t)b * INW + c)
                                 : (h + (size_t)b * HH + (c - INW));
    float4 v0 = *(const float4*)src;
    float4 v1 = *(const float4*)(src + 4);
    bf16x8 ov;
    ov[0] = (bf16)v0.x; ov[1] = (bf16)v0.y; ov[2] = (bf16)v0.z; ov[3] = (bf16)v0.w;
    ov[4] = (bf16)v1.x; ov[5] = (bf16)v1.y; ov[6] = (bf16)v1.z; ov[7] = (bf16)v1.w;
    *(bf16x8*)(comb + e) = ov;
  } else {                             // ---- Wb: sequential-row shuffle ----
    int w   = blockIdx.x - NCB;        // [0, 1280)
    int nt  = w / 40;
    int rem = w - nt * 40;
    int f   = rem >> 2;                // fragment slot 0..9
    int rp  = rem & 3;                 // row-quarter 0..3
    int q   = f / 5;
    int g   = f - q * 5;               // gate: 0=i 1=f 2=o 3=p0 4=p1
    int kk  = tid >> 2;                // k-chunk of 32
    int kq  = tid & 3;                 // k-quad within chunk
    size_t wbase = ((size_t)(nt * FPG + f) * 64 + kk) * 64 + kq * 16;
#pragma unroll
    for (int r4 = 0; r4 < 4; ++r4) {
      int s    = rp * 4 + r4;          // row-in-fragment 0..15
      int hcol = nt * 32 + q * 16 + s;
      const float* src = (g < 3)
          ? (Wg + (size_t)(g * HH + hcol) * KIN + tid * 8)
          : (Wc + (size_t)(2 * hcol + (g - 3)) * KIN + tid * 8);
      float4 v0 = *(const float4*)src;
      float4 v1 = *(const float4*)(src + 4);
      bf16x8 ov;
      ov[0] = (bf16)v0.x; ov[1] = (bf16)v0.y; ov[2] = (bf16)v0.z; ov[3] = (bf16)v0.w;
      ov[4] = (bf16)v1.x; ov[5] = (bf16)v1.y; ov[6] = (bf16)v1.z; ov[7] = (bf16)v1.w;
      *(bf16x8*)(Wb + (wbase + s) * 8) = ov;
    }
  }
}

// ---------------------------------------------------------------------------
// 2. Fused GEMM + LSTM epilogue. R12 = R10 occupancy + B-fragments-in-regs.
//    R10/R11 post-mortem: LDS pipe is the saturated resource — 8 waves x
//    14 ds_read_b128/iter (B tile read 4x-duplicated) + 36 KB gld_lds writes
//    ~ fills the ~1894-cyc iter window; drain/traffic experiments all nulled
//    because they never cut LDS demand. Fix: B consumed in exact fragment
//    order -> each lane loads its own 16B directly from L2-resident Wb
//    (R7's mechanism) at R9/R10's 4 waves/SIMD (R7 lacked it: acc 80 regs).
//    Regs: acc 40 + bfr 40 + af 8 + addr ~20 = ~110 <= 128 cap.
//    LDS demand/iter: 32 KB af reads + 16 KB A writes (~375 cyc) — freed.
//    A via gld_lds, 4-buffer rotation (64 KB, R8-validated): stage t+1 into
//    buf (t+1)&3; overwritten buffer last read 3 barriers ago -> ONE barrier
//    per iter. vmcnt(2): per-thread VMEM order = 10 B-reg loads, then 2
//    A-DMAs (sched_barrier pins it) -> vmcnt(2) completes A(t)+B(t), leaves
//    A(t+1) in flight across the barrier. Compiler auto-waits B-reg uses.
//    Spill tripwire: WRITE_SIZE must stay ~33 MB.
// ---------------------------------------------------------------------------
#define ASZ  8192      // A elems per LDS buffer (16 KB); 4 buffers = 64 KB

__global__ __launch_bounds__(512, 4) void gemm_fused(
    const bf16* __restrict__ A, const bf16* __restrict__ Bm,
    const float* __restrict__ c_prev, const float* __restrict__ bg,
    const float* __restrict__ bc, const float* __restrict__ W1,
    const float* __restrict__ b1, const float* __restrict__ W2,
    const float* __restrict__ b2, float* __restrict__ h_next,
    float* __restrict__ c_next) {
  __shared__ bf16 As2[4 * ASZ];    // 64 KB: four A buffers (rotation)

  const int tid  = threadIdx.x;
  const int wave = tid >> 6;
  const int lane = tid & 63;

  // R5 XCD swizzle (proven): 1024 blocks, 8 XCDs, 128 blocks/XCD, m fastest;
  // each XCD owns nts [4x,4x+4) -> 2.56 MB B slice L2-resident.
  const int bid = blockIdx.y * gridDim.x + blockIdx.x;
  const int swz = (bid & 7) * 128 + (bid >> 3);
  const int m0  = (swz & 31) * 128;
  const int nt  = swz >> 5;

  const int wm = (wave >> 1) * 32;   // wave row origin (4 row-groups of 32)
  const int q  = wave & 1;           // wave col half: which 16 h's
  const int lr = lane & 15;
  const int qd = lane >> 4;

  // B fragment base: elem = ((F*64 + kk)*64 + lane) * 8, F = nt*10 + q*5 + ni
  const bf16* Bq = Bm + (size_t)(nt * FPG + q * 5) * 32768 + (size_t)lane * 8;

  floatx4 acc[2][5] = {};
  bf16x8 bfr[2][5];                  // B fragments for current tile (40 VGPR)

  // Per-thread A staging constants: 1024 slots over 512 threads, 2 each.
  // slot s: row = s>>3, c = (s&7)^(row&7); LDS dest = s*16 B (linear).
  const int as0 = tid;               // slots handled: as0, as0 + 512

  // ---- LOADB(t): 10 x 16B fragment loads into registers ----
#define LOADB(kt)                                                              \
  {                                                                            \
    _Pragma("unroll")                                                          \
    for (int ks = 0; ks < 2; ++ks)                                             \
      _Pragma("unroll")                                                        \
      for (int ni = 0; ni < 5; ++ni)                                           \
        bfr[ks][ni] = *(const bf16x8*)(Bq + (size_t)ni * 32768 +               \
                                       (size_t)((kt) * 2 + ks) * 512);         \
  }

  // ---- STAGEA(bb, kt): 2 gld_lds chunks per thread, XOR-swizzled ----
#define STAGEA(bb, kt)                                                         \
  {                                                                            \
    _Pragma("unroll")                                                          \
    for (int j = 0; j < 2; ++j) {                                              \
      int s   = j * 512 + as0;                                                 \
      int row = s >> 3;                                                        \
      int c   = (s & 7) ^ (row & 7);                                           \
      GLD16(A + (size_t)(m0 + row) * KIN + (kt) * 64 + c * 8,                  \
            As2 + (size_t)(bb) * ASZ + (size_t)(j * 512 + wave * 64) * 8);     \
    }                                                                          \
  }

  // ---- COMPUTE(bb): 2 k-steps x 10 MFMA; A from LDS, B from regs ----
#define COMPUTE(bb)                                                            \
  {                                                                            \
    const bf16* As = As2 + (size_t)(bb) * ASZ;                                 \
    _Pragma("unroll")                                                          \
    for (int ks = 0; ks < 2; ++ks) {                                           \
      bf16x8 af[2];                                                            \
      _Pragma("unroll")                                                        \
      for (int mi = 0; mi < 2; ++mi) {                                         \
        int row  = wm + mi * 16 + lr;                                          \
        int slot = (ks * 4 + qd) ^ (lr & 7);                                   \
        af[mi] = *(const bf16x8*)&As[(row << 6) + (slot << 3)];                \
      }                                                                        \
      _Pragma("unroll")                                                        \
      for (int mi = 0; mi < 2; ++mi)                                           \
        _Pragma("unroll")                                                      \
        for (int ni = 0; ni < 5; ++ni)                                         \
          acc[mi][ni] = __builtin_amdgcn_mfma_f32_16x16x32_bf16(               \
              af[mi], bfr[ks][ni], acc[mi][ni], 0, 0, 0);                      \
    }                                                                          \
  }

  // ---- one iteration: read buf u = t&3, stage t+1 into (u+1)&3 ----
#define ITER(u, t)                                                             \
  {                                                                            \
    LOADB(t);                                 /* 10 B loads (oldest) */        \
    __builtin_amdgcn_sched_barrier(0);                                         \
    int ta = ((t) + 1 < 32) ? (t) + 1 : 31;   /* clamped dead tail DMA */      \
    STAGEA(((u) + 1) & 3, ta);                /* 2 A DMAs (newest) */          \
    asm volatile("s_waitcnt vmcnt(2)" ::: "memory"); /* A(t),B(t) done */      \
    __builtin_amdgcn_s_barrier();                                              \
    __builtin_amdgcn_sched_barrier(0);                                         \
    COMPUTE(u);                                                                \
  }

  // Prologue: A(0) staged; iteration 0's vmcnt(2) covers its completion.
  STAGEA(0, 0);

#pragma unroll 1
  for (int trip = 0; trip < 8; ++trip) {
    const int t0 = trip * 4;
    ITER(0, t0 + 0);
    ITER(1, t0 + 1);
    ITER(2, t0 + 2);
    ITER(3, t0 + 3);
  }

  // Drain the dead tail DMA before LDS dealloc / epilogue.
  asm volatile("s_waitcnt vmcnt(0)" ::: "memory");

  // ---- fused epilogue: all 5 gates of (b, h) live in this lane ----
  const int h   = nt * 32 + q * 16 + lr;
  const float bgi = bg[h];
  const float bgf = bg[HH + h];
  const float bgo = bg[2 * HH + h];
  const float bc0 = bc[2 * h];
  const float bc1 = bc[2 * h + 1];
  const float gb  = b2[0];

  float p0[8], p1[8], ga[8];
#pragma unroll
  for (int mi = 0; mi < 2; ++mi)
#pragma unroll
    for (int r = 0; r < 4; ++r) {
      p0[mi * 4 + r] = acc[mi][3][r] + bc0;
      p1[mi * 4 + r] = acc[mi][4][r] + bc1;
      ga[mi * 4 + r] = gb;
    }
  // inner MLP: k-outer so the 4 uniform weight scalars stay in SGPRs
#pragma unroll
  for (int k = 0; k < KH; ++k) {
    float w0 = W1[2 * k], w1 = W1[2 * k + 1], bk = b1[k], wk = W2[k];
#pragma unroll
    for (int e = 0; e < 8; ++e) {
      float hv = fmaf(p0[e], w0, fmaf(p1[e], w1, bk));
      hv = fmaxf(hv, 0.0f);
      ga[e] = fmaf(hv, wk, ga[e]);
    }
  }

#pragma unroll
  for (int mi = 0; mi < 2; ++mi)
#pragma unroll
    for (int r = 0; r < 4; ++r) {
      int b    = m0 + wm + mi * 16 + qd * 4 + r;
      size_t o = (size_t)b * HH + h;
      float si = 1.0f / (1.0f + __expf(-(acc[mi][0][r] + bgi)));
      float sf = 1.0f / (1.0f + __expf(-(acc[mi][1][r] + bgf)));
      float so = 1.0f / (1.0f + __expf(-(acc[mi][2][r] + bgo)));
      float cn = fmaf(sf, c_prev[o], si * ga[mi * 4 + r]);
      float e2 = __expf(2.0f * cn);          // tanh(cn) = 1 - 2/(e^{2cn}+1)
      float th = 1.0f - 2.0f / (e2 + 1.0f);
      h_next[o] = so * th;
      c_next[o] = cn;
    }
}

// ---------------------------------------------------------------------------
extern "C" void kernel_launch(void* const* d_in, const int* in_sizes, int n_in,
                              void* d_out, int out_size, void* d_ws, size_t ws_size,
                              hipStream_t stream) {
  const float* x      = (const float*)d_in[0];
  const float* h_prev = (const float*)d_in[1];
  const float* c_prev = (const float*)d_in[2];
  const float* Wg     = (const float*)d_in[3];
  const float* bg     = (const float*)d_in[4];
  const float* Wc     = (const float*)d_in[5];
  const float* bc     = (const float*)d_in[6];
  const float* W1     = (const float*)d_in[7];
  const float* b1     = (const float*)d_in[8];
  const float* W2     = (const float*)d_in[9];
  const float* b2     = (const float*)d_in[10];
  float* out = (float*)d_out;

  // workspace layout
  char* ws = (char*)d_ws;
  bf16* comb = (bf16*)ws;                                    // 16 MB
  bf16* Wb   = (bf16*)(ws + (size_t)BB * KIN * 2);           // 20 MB

  // 1. prep (concat + cast + gate-permuted, sequential-read B shuffle)
  prep<<<NCB + NWB, 256, 0, stream>>>(x, h_prev, Wg, Wc, comb, Wb);

  // 2. fused GEMM + epilogue (B-in-regs, A 4-buffer rotation, 8 waves)
  dim3 grid(BB / 128, NTG);
  gemm_fused<<<grid, 512, 0, stream>>>(comb, Wb, c_prev, bg, bc, W1, b1, W2,
                                       b2, out, out + (size_t)BB * HH);
}

// Round 13
// 267.409 us; speedup vs baseline: 1.0373x; 1.0373x over previous
//
#include <hip/hip_runtime.h>
#include <hip/hip_bf16.h>

// Problem constants
#define BB   4096
#define INW  1024
#define HH   1024
#define KIN  2048      // IN + H
#define NG   5120      // 3H + 2H
#define KH   32        // inner hidden
#define FPG  10        // 16-col fragments per 160-col gate-group
#define NTG  32        // number of gate-groups (= H/32)

typedef __bf16 bf16;
typedef __bf16 bf16x4 __attribute__((ext_vector_type(4)));
typedef __bf16 bf16x8 __attribute__((ext_vector_type(8)));
typedef float  floatx4 __attribute__((ext_vector_type(4)));

#define GLD16(gp, lp)                                                          \
  __builtin_amdgcn_global_load_lds(                                            \
      (__attribute__((address_space(1))) const void*)(gp),                     \
      (__attribute__((address_space(3))) void*)(lp), 16, 0, 0)

// ---------------------------------------------------------------------------
// 1. prep (unchanged — sequential-row B shuffle, coalesced comb).
//    Wb chunk layout [F][kk][lane] with F = nt*10+f: chunk = (F*64 + kk)*64 +
//    (kq*16 + s) holds B[hcol = nt*32 + (f/5)*16 + s, gate f%5]
//    [k = kk*32 + kq*8 .. +7].
// ---------------------------------------------------------------------------
#define NCB  4096      // comb blocks: BB*KIN/8 threads / 256
#define NWB  1280      // Wb blocks: 32 nt x 10 f x 4 row-quarters

__global__ __launch_bounds__(256) void prep(
    const float* __restrict__ x, const float* __restrict__ h,
    const float* __restrict__ Wg, const float* __restrict__ Wc,
    bf16* __restrict__ comb, bf16* __restrict__ Wb) {
  int tid = threadIdx.x;
  if (blockIdx.x < NCB) {              // ---- comb: concat + cast ----
    int e = (blockIdx.x * 256 + tid) * 8;
    int b = e >> 11;          // / KIN
    int c = e & (KIN - 1);
    const float* src = (c < INW) ? (x + (size_t)b * INW + c)
                                 : (h + (size_t)b * HH + (c - INW));
    float4 v0 = *(const float4*)src;
    float4 v1 = *(const float4*)(src + 4);
    bf16x8 ov;
    ov[0] = (bf16)v0.x; ov[1] = (bf16)v0.y; ov[2] = (bf16)v0.z; ov[3] = (bf16)v0.w;
    ov[4] = (bf16)v1.x; ov[5] = (bf16)v1.y; ov[6] = (bf16)v1.z; ov[7] = (bf16)v1.w;
    *(bf16x8*)(comb + e) = ov;
  } else {                             // ---- Wb: sequential-row shuffle ----
    int w   = blockIdx.x - NCB;        // [0, 1280)
    int nt  = w / 40;
    int rem = w - nt * 40;
    int f   = rem >> 2;                // fragment slot 0..9
    int rp  = rem & 3;                 // row-quarter 0..3
    int q   = f / 5;
    int g   = f - q * 5;               // gate: 0=i 1=f 2=o 3=p0 4=p1
    int kk  = tid >> 2;                // k-chunk of 32
    int kq  = tid & 3;                 // k-quad within chunk
    size_t wbase = ((size_t)(nt * FPG + f) * 64 + kk) * 64 + kq * 16;
#pragma unroll
    for (int r4 = 0; r4 < 4; ++r4) {
      int s    = rp * 4 + r4;          // row-in-fragment 0..15
      int hcol = nt * 32 + q * 16 + s;
      const float* src = (g < 3)
          ? (Wg + (size_t)(g * HH + hcol) * KIN + tid * 8)
          : (Wc + (size_t)(2 * hcol + (g - 3)) * KIN + tid * 8);
      float4 v0 = *(const float4*)src;
      float4 v1 = *(const float4*)(src + 4);
      bf16x8 ov;
      ov[0] = (bf16)v0.x; ov[1] = (bf16)v0.y; ov[2] = (bf16)v0.z; ov[3] = (bf16)v0.w;
      ov[4] = (bf16)v1.x; ov[5] = (bf16)v1.y; ov[6] = (bf16)v1.z; ov[7] = (bf16)v1.w;
      *(bf16x8*)(Wb + (wbase + s) * 8) = ov;
    }
  }
}

// ---------------------------------------------------------------------------
// 2. Fused GEMM + LSTM epilogue. R13 = R10 geometry + the 8-phase schedule
//    (T3+T4 fine interleave, depth-2 prefetch, never-0 vmcnt, T5 setprio).
//    R12 reverted (B-reg loads 4x-duplicated from L2 -> L2-BW bound).
//    Schedule per K-tile t (2 phases, one per ks):
//      ph0: ds_read frags(ks0, buf u) ; STAGE half1(t+2 -> buf v) ;
//           barrier ; setprio1 ; 10 MFMA ; setprio0
//      ph1: ds_read frags(ks1) ; STAGE half2(t+2) ;
//           vmcnt(A:4 | B:5)  [= tile t+1 done, t+2's 4|5 in flight] ;
//           barrier ; setprio1 ; 10 MFMA ; setprio0
//    3-buffer rotation (u=t%3 read, v=(t+2)%3 fill): buffer v was last read
//    at tile t-1, whose ph1 barrier precedes ph0(t)'s stage issue. The vmcnt
//    never drains to 0 in the loop (m218's lever); counts are exact (loop
//    body has no other VMEM). sched_barrier(0) pins every s_barrier
//    (raw s_barrier has no compiler memory semantics). LDS 3 x 36 KB =
//    108 KB -> 1 block/CU, 8 waves; the per-phase interleave carries the
//    overlap (m201 runs the same occupancy at 62% MfmaUtil).
//    Spill tripwire: WRITE_SIZE must stay ~33 MB.
// ---------------------------------------------------------------------------
#define ASZ  8192      // A elems per buffer (16 KB)
#define BSZ  10240     // B elems per buffer (20 KB)
#define BUF  (ASZ + BSZ)

__global__ __launch_bounds__(512, 2) void gemm_fused(
    const bf16* __restrict__ A, const bf16* __restrict__ Bm,
    const float* __restrict__ c_prev, const float* __restrict__ bg,
    const float* __restrict__ bc, const float* __restrict__ W1,
    const float* __restrict__ b1, const float* __restrict__ W2,
    const float* __restrict__ b2, float* __restrict__ h_next,
    float* __restrict__ c_next) {
  __shared__ bf16 sh[3 * BUF];     // 108 KB: three {A 16K + B 20K} buffers

  const int tid  = threadIdx.x;
  const int wave = tid >> 6;
  const int lane = tid & 63;

  // R5 XCD swizzle (proven): 1024 blocks, 8 XCDs, 128 blocks/XCD, m fastest.
  const int bid = blockIdx.y * gridDim.x + blockIdx.x;
  const int swz = (bid & 7) * 128 + (bid >> 3);
  const int m0  = (swz & 31) * 128;
  const int nt  = swz >> 5;

  const int wm = (wave >> 1) * 32;   // wave row origin (4 row-groups of 32)
  const int q  = wave & 1;           // wave col half: which 16 h's
  const int lr = lane & 15;
  const int qd = lane >> 4;

  floatx4 acc[2][5] = {};

  // ---- STG(bb, kt, JA0..JA1, JB0..JB1): role-split staging (R10 layout) ----
  // A-waves (0-3): slots s = j*256 + tid, row = s>>3, c = (s&7)^(row&7)
  // B-waves (4-7): slots s = j*256 + wv*64 + lane, chunk c20 = j*4 + wv
#define STG(bb, kt, JA0, JA1, JB0, JB1)                                        \
  {                                                                            \
    if (wave < 4) {                                                            \
      _Pragma("unroll")                                                        \
      for (int j = (JA0); j <= (JA1); ++j) {                                   \
        int s   = j * 256 + tid;                                               \
        int row = s >> 3;                                                      \
        int c   = (s & 7) ^ (row & 7);                                         \
        GLD16(A + (size_t)(m0 + row) * KIN + (kt) * 64 + c * 8,                \
              sh + (size_t)(bb) * BUF + (size_t)s * 8);                        \
      }                                                                        \
    } else {                                                                   \
      int wv = wave - 4;                                                       \
      _Pragma("unroll")                                                        \
      for (int j = (JB0); j <= (JB1); ++j) {                                   \
        int s   = j * 256 + wv * 64 + lane;                                    \
        int c20 = j * 4 + wv;                                                  \
        int f   = c20 >> 1;                                                    \
        int ks2 = c20 & 1;                                                     \
        size_t gchunk = (size_t)(nt * FPG + f) * 64 + ((kt) * 2 + ks2);        \
        GLD16(Bm + (gchunk * 64 + lane) * 8,                                   \
              sh + (size_t)(bb) * BUF + ASZ + (size_t)s * 8);                  \
      }                                                                        \
    }                                                                          \
  }

  // ---- LDFRAG(af, bf, ks): fragment ds_reads from As/Bs (in scope) ----
#define LDFRAG(af, bf, ks)                                                     \
  {                                                                            \
    _Pragma("unroll")                                                          \
    for (int mi = 0; mi < 2; ++mi) {                                           \
      int row  = wm + mi * 16 + lr;                                            \
      int slot = ((ks) * 4 + qd) ^ (lr & 7);                                   \
      af[mi] = *(const bf16x8*)&As[(row << 6) + (slot << 3)];                  \
    }                                                                          \
    _Pragma("unroll")                                                          \
    for (int ni = 0; ni < 5; ++ni) {                                           \
      int chunk = ((q * 5 + ni) << 1) + (ks);                                  \
      bf[ni] = *(const bf16x8*)&Bs[(chunk << 9) + (lane << 3)];                \
    }                                                                          \
  }

#define MFMA10(af, bf)                                                         \
  {                                                                            \
    _Pragma("unroll")                                                          \
    for (int mi = 0; mi < 2; ++mi)                                             \
      _Pragma("unroll")                                                        \
      for (int ni = 0; ni < 5; ++ni)                                           \
        acc[mi][ni] = __builtin_amdgcn_mfma_f32_16x16x32_bf16(                 \
            af[mi], bf[ni], acc[mi][ni], 0, 0, 0);                             \
  }

#define VMW()                                                                  \
  {                                                                            \
    if (wave < 4) asm volatile("s_waitcnt vmcnt(4)" ::: "memory");             \
    else          asm volatile("s_waitcnt vmcnt(5)" ::: "memory");             \
  }

#define BAR()                                                                  \
  {                                                                            \
    __builtin_amdgcn_sched_barrier(0);                                         \
    __builtin_amdgcn_s_barrier();                                              \
    __builtin_amdgcn_sched_barrier(0);                                         \
  }

  // Prologue: tiles 0,1 fully staged; wait tile0 (tile1 stays in flight).
  STG(0, 0, 0, 3, 0, 4);
  STG(1, 1, 0, 3, 0, 4);
  VMW();
  BAR();

  int u = 0, v = 2;                  // read buf = t%3, fill buf = (t+2)%3
#pragma unroll 1
  for (int t = 0; t < 32; ++t) {
    const bf16* As = sh + (size_t)u * BUF;
    const bf16* Bs = As + ASZ;
    const int ts = (t + 2 < 32) ? t + 2 : 31;   // clamped dead tail stage
    // ---------------- phase 0 (ks = 0) ----------------
    {
      bf16x8 af0[2], bf0[5];
      LDFRAG(af0, bf0, 0);
      STG(v, ts, 0, 1, 0, 1);        // half1 of tile t+2
      BAR();
      __builtin_amdgcn_s_setprio(1);
      MFMA10(af0, bf0);
      __builtin_amdgcn_s_setprio(0);
      __builtin_amdgcn_sched_barrier(0);
    }
    // ---------------- phase 1 (ks = 1) ----------------
    {
      bf16x8 af1[2], bf1[5];
      LDFRAG(af1, bf1, 1);
      STG(v, ts, 2, 3, 2, 4);        // half2 of tile t+2
      VMW();                         // tile t+1 complete; t+2 in flight
      BAR();
      __builtin_amdgcn_s_setprio(1);
      MFMA10(af1, bf1);
      __builtin_amdgcn_s_setprio(0);
      __builtin_amdgcn_sched_barrier(0);
    }
    u = (u == 2) ? 0 : u + 1;
    v = (v == 2) ? 0 : v + 1;
  }
  // Drain dead tail DMAs before the epilogue.
  asm volatile("s_waitcnt vmcnt(0)" ::: "memory");

  // ---- fused epilogue: all 5 gates of (b, h) live in this lane ----
  const int h   = nt * 32 + q * 16 + lr;
  const float bgi = bg[h];
  const float bgf = bg[HH + h];
  const float bgo = bg[2 * HH + h];
  const float bc0 = bc[2 * h];
  const float bc1 = bc[2 * h + 1];
  const float gb  = b2[0];

  float p0[8], p1[8], ga[8];
#pragma unroll
  for (int mi = 0; mi < 2; ++mi)
#pragma unroll
    for (int r = 0; r < 4; ++r) {
      p0[mi * 4 + r] = acc[mi][3][r] + bc0;
      p1[mi * 4 + r] = acc[mi][4][r] + bc1;
      ga[mi * 4 + r] = gb;
    }
  // inner MLP: k-outer so the 4 uniform weight scalars stay in SGPRs
#pragma unroll
  for (int k = 0; k < KH; ++k) {
    float w0 = W1[2 * k], w1 = W1[2 * k + 1], bk = b1[k], wk = W2[k];
#pragma unroll
    for (int e = 0; e < 8; ++e) {
      float hv = fmaf(p0[e], w0, fmaf(p1[e], w1, bk));
      hv = fmaxf(hv, 0.0f);
      ga[e] = fmaf(hv, wk, ga[e]);
    }
  }

#pragma unroll
  for (int mi = 0; mi < 2; ++mi)
#pragma unroll
    for (int r = 0; r < 4; ++r) {
      int b    = m0 + wm + mi * 16 + qd * 4 + r;
      size_t o = (size_t)b * HH + h;
      float si = 1.0f / (1.0f + __expf(-(acc[mi][0][r] + bgi)));
      float sf = 1.0f / (1.0f + __expf(-(acc[mi][1][r] + bgf)));
      float so = 1.0f / (1.0f + __expf(-(acc[mi][2][r] + bgo)));
      float cn = fmaf(sf, c_prev[o], si * ga[mi * 4 + r]);
      float e2 = __expf(2.0f * cn);          // tanh(cn) = 1 - 2/(e^{2cn}+1)
      float th = 1.0f - 2.0f / (e2 + 1.0f);
      h_next[o] = so * th;
      c_next[o] = cn;
    }
}

// ---------------------------------------------------------------------------
extern "C" void kernel_launch(void* const* d_in, const int* in_sizes, int n_in,
                              void* d_out, int out_size, void* d_ws, size_t ws_size,
                              hipStream_t stream) {
  const float* x      = (const float*)d_in[0];
  const float* h_prev = (const float*)d_in[1];
  const float* c_prev = (const float*)d_in[2];
  const float* Wg     = (const float*)d_in[3];
  const float* bg     = (const float*)d_in[4];
  const float* Wc     = (const float*)d_in[5];
  const float* bc     = (const float*)d_in[6];
  const float* W1     = (const float*)d_in[7];
  const float* b1     = (const float*)d_in[8];
  const float* W2     = (const float*)d_in[9];
  const float* b2     = (const float*)d_in[10];
  float* out = (float*)d_out;

  // workspace layout
  char* ws = (char*)d_ws;
  bf16* comb = (bf16*)ws;                                    // 16 MB
  bf16* Wb   = (bf16*)(ws + (size_t)BB * KIN * 2);           // 20 MB

  // 1. prep (concat + cast + gate-permuted, sequential-read B shuffle)
  prep<<<NCB + NWB, 256, 0, stream>>>(x, h_prev, Wg, Wc, comb, Wb);

  // 2. fused GEMM + epilogue (8-phase fine-interleaved, 3-buffer rotation)
  dim3 grid(BB / 128, NTG);
  gemm_fused<<<grid, 512, 0, stream>>>(comb, Wb, c_prev, bg, bc, W1, b1, W2,
                                       b2, out, out + (size_t)BB * HH);
}

// Round 14
// 244.436 us; speedup vs baseline: 1.1348x; 1.0940x over previous
//
#include <hip/hip_runtime.h>
#include <hip/hip_bf16.h>

// Problem constants
#define BB   4096
#define INW  1024
#define HH   1024
#define KIN  2048      // IN + H
#define NG   5120      // 3H + 2H
#define KH   32        // inner hidden
#define FPG  10        // 16-col fragments per 160-col gate-group
#define NTG  32        // number of gate-groups (= H/32)

typedef __bf16 bf16;
typedef __bf16 bf16x4 __attribute__((ext_vector_type(4)));
typedef __bf16 bf16x8 __attribute__((ext_vector_type(8)));
typedef float  floatx4 __attribute__((ext_vector_type(4)));

#define GLD16(gp, lp)                                                          \
  __builtin_amdgcn_global_load_lds(                                            \
      (__attribute__((address_space(1))) const void*)(gp),                     \
      (__attribute__((address_space(3))) void*)(lp), 16, 0, 0)

// ---------------------------------------------------------------------------
// 1. prep (unchanged — sequential-row B shuffle, coalesced comb).
//    Wb chunk layout [F][kk][lane] with F = nt*10+f: chunk = (F*64 + kk)*64 +
//    (kq*16 + s) holds B[hcol = nt*32 + (f/5)*16 + s, gate f%5]
//    [k = kk*32 + kq*8 .. +7].
// ---------------------------------------------------------------------------
#define NCB  4096      // comb blocks: BB*KIN/8 threads / 256
#define NWB  1280      // Wb blocks: 32 nt x 10 f x 4 row-quarters

__global__ __launch_bounds__(256) void prep(
    const float* __restrict__ x, const float* __restrict__ h,
    const float* __restrict__ Wg, const float* __restrict__ Wc,
    bf16* __restrict__ comb, bf16* __restrict__ Wb) {
  int tid = threadIdx.x;
  if (blockIdx.x < NCB) {              // ---- comb: concat + cast ----
    int e = (blockIdx.x * 256 + tid) * 8;
    int b = e >> 11;          // / KIN
    int c = e & (KIN - 1);
    const float* src = (c < INW) ? (x + (size_t)b * INW + c)
                                 : (h + (size_t)b * HH + (c - INW));
    float4 v0 = *(const float4*)src;
    float4 v1 = *(const float4*)(src + 4);
    bf16x8 ov;
    ov[0] = (bf16)v0.x; ov[1] = (bf16)v0.y; ov[2] = (bf16)v0.z; ov[3] = (bf16)v0.w;
    ov[4] = (bf16)v1.x; ov[5] = (bf16)v1.y; ov[6] = (bf16)v1.z; ov[7] = (bf16)v1.w;
    *(bf16x8*)(comb + e) = ov;
  } else {                             // ---- Wb: sequential-row shuffle ----
    int w   = blockIdx.x - NCB;        // [0, 1280)
    int nt  = w / 40;
    int rem = w - nt * 40;
    int f   = rem >> 2;                // fragment slot 0..9
    int rp  = rem & 3;                 // row-quarter 0..3
    int q   = f / 5;
    int g   = f - q * 5;               // gate: 0=i 1=f 2=o 3=p0 4=p1
    int kk  = tid >> 2;                // k-chunk of 32
    int kq  = tid & 3;                 // k-quad within chunk
    size_t wbase = ((size_t)(nt * FPG + f) * 64 + kk) * 64 + kq * 16;
#pragma unroll
    for (int r4 = 0; r4 < 4; ++r4) {
      int s    = rp * 4 + r4;          // row-in-fragment 0..15
      int hcol = nt * 32 + q * 16 + s;
      const float* src = (g < 3)
          ? (Wg + (size_t)(g * HH + hcol) * KIN + tid * 8)
          : (Wc + (size_t)(2 * hcol + (g - 3)) * KIN + tid * 8);
      float4 v0 = *(const float4*)src;
      float4 v1 = *(const float4*)(src + 4);
      bf16x8 ov;
      ov[0] = (bf16)v0.x; ov[1] = (bf16)v0.y; ov[2] = (bf16)v0.z; ov[3] = (bf16)v0.w;
      ov[4] = (bf16)v1.x; ov[5] = (bf16)v1.y; ov[6] = (bf16)v1.z; ov[7] = (bf16)v1.w;
      *(bf16x8*)(Wb + (wbase + s) * 8) = ov;
    }
  }
}

// ---------------------------------------------------------------------------
// 2. Fused GEMM + LSTM epilogue. R14 = R9/R10 geometry with BK=128.
//    R13 (8-phase @ 1 block/CU) regressed -> reverted; R10 (BK=64 dbuf,
//    2 blocks/CU, 4 waves/SIMD) stands at 101.7us / 850 TF. The proven axis
//    is fatter compute windows per drain + co-resident overlap: BK=128
//    halves the barrier pairs (16 vs 32) and doubles MFMA per window
//    (80/wave-pair) while the 72 KB single buffer still fits 2 blocks/CU
//    (144 <= 160 KB) at 4 waves/SIMD (regs ~95 <= 128 cap -> no spill).
//    Co-resident sibling covers the stage drain (m114) as in R9/R10.
//    A XOR swizzle generalized to 16 chunks/row: slot = c ^ (row&15)
//    (R0-proven); B = 40 linear 1 KB chunks, c40 = f*4 + ks.
//    Spill tripwire: WRITE_SIZE must stay ~33 MB.
// ---------------------------------------------------------------------------
#define ASZ  16384     // A elems (32 KB: 128 rows x 128)
#define BSZ  20480     // B elems (40 KB: 40 chunks x 512)

__global__ __launch_bounds__(512, 4) void gemm_fused(
    const bf16* __restrict__ A, const bf16* __restrict__ Bm,
    const float* __restrict__ c_prev, const float* __restrict__ bg,
    const float* __restrict__ bc, const float* __restrict__ W1,
    const float* __restrict__ b1, const float* __restrict__ W2,
    const float* __restrict__ b2, float* __restrict__ h_next,
    float* __restrict__ c_next) {
  __shared__ bf16 As[ASZ];         // 32 KB A tile (16-chunk XOR swizzle)
  __shared__ bf16 Bs[BSZ];         // 40 KB B tile (40 chunks of 1 KB)

  const int tid  = threadIdx.x;
  const int wave = tid >> 6;
  const int lane = tid & 63;

  // R5 XCD swizzle (proven): 1024 blocks, 8 XCDs, 128 blocks/XCD, m fastest.
  const int bid = blockIdx.y * gridDim.x + blockIdx.x;
  const int swz = (bid & 7) * 128 + (bid >> 3);
  const int m0  = (swz & 31) * 128;
  const int nt  = swz >> 5;

  const int wm = (wave >> 1) * 32;   // wave row origin (4 row-groups of 32)
  const int q  = wave & 1;           // wave col half: which 16 h's
  const int lr = lane & 15;
  const int qd = lane >> 4;

  floatx4 acc[2][5] = {};

  for (int kt = 0; kt < KIN / 128; ++kt) {    // 16 iterations of BK=128
    __syncthreads();  // previous tile's LDS reads complete before overwrite

    if (wave < 4) {
      // ---- stage A: 2048 slots (128 rows x 16 chunks), XOR-swizzled ----
#pragma unroll
      for (int j = 0; j < 8; ++j) {
        int s   = j * 256 + tid;         // tid in [0,256)
        int row = s >> 4;
        int c   = (s & 15) ^ (row & 15);
        GLD16(A + (size_t)(m0 + row) * KIN + kt * 128 + c * 8,
              As + (size_t)(j * 256 + wave * 64) * 8);
      }
    } else {
      // ---- stage B: 2560 slots (40 chunks of 1 KB), linear ----
      int wv = wave - 4;
#pragma unroll
      for (int j = 0; j < 10; ++j) {
        int s   = j * 256 + wv * 64 + lane;  // 0..2559
        int c40 = j * 4 + wv;                // chunk 0..39 = f*4 + ks
        int f   = c40 >> 2;
        int ks  = c40 & 3;
        size_t gchunk = (size_t)(nt * FPG + f) * 64 + (kt * 4 + ks);
        GLD16(Bm + (gchunk * 64 + lane) * 8, Bs + (size_t)s * 8);
      }
    }
    __syncthreads();

#pragma unroll
    for (int ks = 0; ks < 4; ++ks) {    // 4 k-steps of 32
      bf16x8 af[2];
#pragma unroll
      for (int mi = 0; mi < 2; ++mi) {
        int row  = wm + mi * 16 + lr;
        int slot = (ks * 4 + qd) ^ lr;  // row&15 == lr, 16-chunk swizzle
        af[mi] = *(const bf16x8*)&As[(row << 7) + (slot << 3)];
      }
      bf16x8 bfr[5];
#pragma unroll
      for (int ni = 0; ni < 5; ++ni) {
        int chunk = ((q * 5 + ni) << 2) + ks;
        bfr[ni] = *(const bf16x8*)&Bs[(chunk << 9) + (lane << 3)];
      }
#pragma unroll
      for (int mi = 0; mi < 2; ++mi)
#pragma unroll
        for (int ni = 0; ni < 5; ++ni)
          acc[mi][ni] = __builtin_amdgcn_mfma_f32_16x16x32_bf16(
              af[mi], bfr[ni], acc[mi][ni], 0, 0, 0);
    }
  }

  // ---- fused epilogue: all 5 gates of (b, h) live in this lane ----
  const int h   = nt * 32 + q * 16 + lr;
  const float bgi = bg[h];
  const float bgf = bg[HH + h];
  const float bgo = bg[2 * HH + h];
  const float bc0 = bc[2 * h];
  const float bc1 = bc[2 * h + 1];
  const float gb  = b2[0];

  float p0[8], p1[8], ga[8];
#pragma unroll
  for (int mi = 0; mi < 2; ++mi)
#pragma unroll
    for (int r = 0; r < 4; ++r) {
      p0[mi * 4 + r] = acc[mi][3][r] + bc0;
      p1[mi * 4 + r] = acc[mi][4][r] + bc1;
      ga[mi * 4 + r] = gb;
    }
  // inner MLP: k-outer so the 4 uniform weight scalars stay in SGPRs
#pragma unroll
  for (int k = 0; k < KH; ++k) {
    float w0 = W1[2 * k], w1 = W1[2 * k + 1], bk = b1[k], wk = W2[k];
#pragma unroll
    for (int e = 0; e < 8; ++e) {
      float hv = fmaf(p0[e], w0, fmaf(p1[e], w1, bk));
      hv = fmaxf(hv, 0.0f);
      ga[e] = fmaf(hv, wk, ga[e]);
    }
  }

#pragma unroll
  for (int mi = 0; mi < 2; ++mi)
#pragma unroll
    for (int r = 0; r < 4; ++r) {
      int b    = m0 + wm + mi * 16 + qd * 4 + r;
      size_t o = (size_t)b * HH + h;
      float si = 1.0f / (1.0f + __expf(-(acc[mi][0][r] + bgi)));
      float sf = 1.0f / (1.0f + __expf(-(acc[mi][1][r] + bgf)));
      float so = 1.0f / (1.0f + __expf(-(acc[mi][2][r] + bgo)));
      float cn = fmaf(sf, c_prev[o], si * ga[mi * 4 + r]);
      float e2 = __expf(2.0f * cn);          // tanh(cn) = 1 - 2/(e^{2cn}+1)
      float th = 1.0f - 2.0f / (e2 + 1.0f);
      h_next[o] = so * th;
      c_next[o] = cn;
    }
}

// ---------------------------------------------------------------------------
extern "C" void kernel_launch(void* const* d_in, const int* in_sizes, int n_in,
                              void* d_out, int out_size, void* d_ws, size_t ws_size,
                              hipStream_t stream) {
  const float* x      = (const float*)d_in[0];
  const float* h_prev = (const float*)d_in[1];
  const float* c_prev = (const float*)d_in[2];
  const float* Wg     = (const float*)d_in[3];
  const float* bg     = (const float*)d_in[4];
  const float* Wc     = (const float*)d_in[5];
  const float* bc     = (const float*)d_in[6];
  const float* W1     = (const float*)d_in[7];
  const float* b1     = (const float*)d_in[8];
  const float* W2     = (const float*)d_in[9];
  const float* b2     = (const float*)d_in[10];
  float* out = (float*)d_out;

  // workspace layout
  char* ws = (char*)d_ws;
  bf16* comb = (bf16*)ws;                                    // 16 MB
  bf16* Wb   = (bf16*)(ws + (size_t)BB * KIN * 2);           // 20 MB

  // 1. prep (concat + cast + gate-permuted, sequential-read B shuffle)
  prep<<<NCB + NWB, 256, 0, stream>>>(x, h_prev, Wg, Wc, comb, Wb);

  // 2. fused GEMM + epilogue (BK=128 single-buffered, 2 blocks/CU)
  dim3 grid(BB / 128, NTG);
  gemm_fused<<<grid, 512, 0, stream>>>(comb, Wb, c_prev, bg, bc, W1, b1, W2,
                                       b2, out, out + (size_t)BB * HH);
}